// Round 5
// baseline (3168.624 us; speedup 1.0000x reference)
//
#include <hip/hip_runtime.h>
#include <float.h>
#include <math.h>
#include <stdint.h>

#define M_ROWS 32768
#define K_CODES 8192
#define DDIM 256
#define BM 64
#define BN 64
#define NTILES (K_CODES / BN)   // 128
#define DELTA 0.009f
#define NCAND 8

typedef __attribute__((ext_vector_type(8))) short short8;
typedef __attribute__((ext_vector_type(4))) float f32x4;

__device__ inline unsigned short f2bf(float f) {
    unsigned u = __float_as_uint(f);
    return (unsigned short)((u + 0x7fffu + ((u >> 16) & 1u)) >> 16);
}
__device__ inline unsigned fkey(float f) {
    unsigned u = __float_as_uint(f);
    return u ^ ((unsigned)((int)u >> 31) | 0x80000000u);
}
__device__ inline float fkey_inv(unsigned k) {
    unsigned u = (k & 0x80000000u) ? (k ^ 0x80000000u) : ~k;
    return __uint_as_float(u);
}

#define GLOAD16(gsrc, ldst)                                                     \
    __builtin_amdgcn_global_load_lds(                                           \
        (const __attribute__((address_space(1))) void*)(gsrc),                  \
        (__attribute__((address_space(3))) void*)(ldst), 16, 0, 0)

// ---------------- kernel 1: normalize E -> En (fp32) + En_b (bf16) ----------------
__global__ __launch_bounds__(256) void k_norm_E(const float* __restrict__ E,
                                                float* __restrict__ En,
                                                unsigned short* __restrict__ En_b) {
    int wid  = threadIdx.x >> 6;
    int lane = threadIdx.x & 63;
    int row  = blockIdx.x * 4 + wid;
    const float* e = E + (size_t)row * DDIM;
    float v[4];
    float ssq = 0.f;
#pragma unroll
    for (int p = 0; p < 4; ++p) { v[p] = e[lane + 64 * p]; ssq += v[p] * v[p]; }
#pragma unroll
    for (int off = 32; off >= 1; off >>= 1) ssq += __shfl_xor(ssq, off);
    float inv = 1.f / fmaxf(sqrtf(ssq), 1e-8f);
    float* o = En + (size_t)row * DDIM;
    unsigned short* ob = En_b + (size_t)row * DDIM;
#pragma unroll
    for (int p = 0; p < 4; ++p) {
        float nv = v[p] * inv;
        o[lane + 64 * p]  = nv;
        ob[lane + 64 * p] = f2bf(nv);
    }
}

// ---------------- kernel 1b: normalize z -> z_nb (bf16) ----------------
__global__ __launch_bounds__(256) void k_norm_z(const float* __restrict__ z,
                                                unsigned short* __restrict__ z_nb) {
    int wid  = threadIdx.x >> 6;
    int lane = threadIdx.x & 63;
    int row  = blockIdx.x * 4 + wid;
    const float* zr = z + (size_t)row * DDIM;
    float v[4];
    float ssq = 0.f;
#pragma unroll
    for (int p = 0; p < 4; ++p) { v[p] = zr[lane + 64 * p]; ssq += v[p] * v[p]; }
#pragma unroll
    for (int off = 32; off >= 1; off >>= 1) ssq += __shfl_xor(ssq, off);
    float inv = 1.f / fmaxf(sqrtf(ssq), 1e-8f);
    unsigned short* o = z_nb + (size_t)row * DDIM;
#pragma unroll
    for (int p = 0; p < 4; ++p) o[lane + 64 * p] = f2bf(v[p] * inv);
}

// ---------------- kernel 2: MFMA filter, register top-2, end-phase candidates ----
// 512 thr = 8 waves: wr = wid>>2 (2 row-halves of BM=64), wc = wid&3 (4 col-16s).
// A fragments direct from global z_nb; B double-buffered in LDS (swizzled).
// Loop body: prefetch-issue, 8 ds_read_b128, 16 MFMA, register top-2 fold, barrier.
__global__ __launch_bounds__(512, 4) void k_cand(
    const unsigned short* __restrict__ z_nb,
    const unsigned short* __restrict__ En_b,
    unsigned char* __restrict__ cand_cnt,
    int* __restrict__ cand_k) {

    __shared__ __attribute__((aligned(16))) char Bs[2][32768];
    __shared__ unsigned rowmaxKey[BM];
    __shared__ int cnt[BM];
    __shared__ int flagArr[BM];
    __shared__ int list[BM][16];

    const int tid  = threadIdx.x;
    const int lane = tid & 63;
    const int wid  = tid >> 6;
    const int wr   = wid >> 2;
    const int wc   = wid & 3;
    const int lo   = lane & 15;
    const int hi   = lane >> 4;
    const int m0   = blockIdx.x * BM;

    if (tid < BM) { cnt[tid] = 0; rowmaxKey[tid] = 0u; flagArr[tid] = 0; }

    const char* eb = (const char*)En_b;

    // ---- stage B tile 0 (32 KB: 32 chunks of 1 KB) ----
#pragma unroll
    for (int i = 0; i < 4; ++i) {
        int chunk = i * 8 + wid;            // 0..31
        int G   = chunk * 64 + lane;
        int row = G >> 5;
        int g   = (G & 31) ^ (row & 7);
        GLOAD16(eb + (size_t)row * 512 + g * 16, &Bs[0][0] + chunk * 1024);
    }

    // ---- A fragments direct from global: af[mi][ks] ----
    short8 af[2][8];
#pragma unroll
    for (int mi = 0; mi < 2; ++mi) {
        const unsigned short* zr = z_nb + (size_t)(m0 + wr * 32 + mi * 16 + lo) * DDIM;
#pragma unroll
        for (int ks = 0; ks < 8; ++ks)
            af[mi][ks] = *(const short8*)&zr[(ks * 4 + hi) * 8];
    }

    // per-lane top-2 per slot (slot = mi*4+r; row = wr*32+mi*16+hi*4+r)
    float v1[8], v2[8];
    int   kp[8];                   // k1 | (k2<<16)
#pragma unroll
    for (int s = 0; s < 8; ++s) { v1[s] = -FLT_MAX; v2[s] = -FLT_MAX; kp[s] = 0; }

    asm volatile("s_waitcnt vmcnt(0)");
    __syncthreads();

    int cur = 0;
    for (int t = 0; t < NTILES; ++t) {
        if (t + 1 < NTILES) {
            int kt1 = (t + 1) * BN;
            char* dst = &Bs[cur ^ 1][0];
#pragma unroll
            for (int i = 0; i < 4; ++i) {
                int chunk = i * 8 + wid;
                int G   = chunk * 64 + lane;
                int row = G >> 5;
                int g   = (G & 31) ^ (row & 7);
                GLOAD16(eb + (size_t)(kt1 + row) * 512 + g * 16, dst + chunk * 1024);
            }
        }

        f32x4 acc[2];
        acc[0] = (f32x4){0.f, 0.f, 0.f, 0.f};
        acc[1] = (f32x4){0.f, 0.f, 0.f, 0.f};

        const unsigned short* Bc = (const unsigned short*)&Bs[cur][0];
        const int brow = wc * 16 + lo;
        const int bsw  = brow & 7;
#pragma unroll
        for (int ks = 0; ks < 8; ++ks) {
            int g = (ks * 4 + hi) ^ bsw;
            short8 bf = *(const short8*)&Bc[brow * 256 + g * 8];
            acc[0] = __builtin_amdgcn_mfma_f32_16x16x32_bf16(af[0][ks], bf, acc[0], 0, 0, 0);
            acc[1] = __builtin_amdgcn_mfma_f32_16x16x32_bf16(af[1][ks], bf, acc[1], 0, 0, 0);
        }

        const int kv = t * BN + wc * 16 + lo;
#pragma unroll
        for (int mi = 0; mi < 2; ++mi)
#pragma unroll
            for (int r = 0; r < 4; ++r) {
                int s = mi * 4 + r;
                float v = acc[mi][r];
                if (v > v1[s])      { v2[s] = v1[s]; v1[s] = v; kp[s] = (kp[s] << 16) | kv; }
                else if (v > v2[s]) { v2[s] = v;     kp[s] = (kp[s] & 0xffff) | (kv << 16); }
            }

        __syncthreads();
        cur ^= 1;
    }

    // ---- end phase: row max -> threshold -> candidate emit ----
#pragma unroll
    for (int s = 0; s < 8; ++s) {
        float w = v1[s];
        w = fmaxf(w, __shfl_xor(w, 1));
        w = fmaxf(w, __shfl_xor(w, 2));
        w = fmaxf(w, __shfl_xor(w, 4));
        w = fmaxf(w, __shfl_xor(w, 8));
        if (lo == 0) {
            int row = wr * 32 + (s >> 2) * 16 + hi * 4 + (s & 3);
            atomicMax(&rowmaxKey[row], fkey(w));
        }
    }
    __syncthreads();

#pragma unroll
    for (int s = 0; s < 8; ++s) {
        int row = wr * 32 + (s >> 2) * 16 + hi * 4 + (s & 3);
        float thr = fkey_inv(rowmaxKey[row]) - DELTA;
        if (v1[s] >= thr) {
            int pos = atomicAdd(&cnt[row], 1);
            if (pos < 16) list[row][pos] = kp[s] & 0xffff;
        }
        if (v2[s] >= thr) {
            // hidden-3rd risk: lane's unseen 3rd value could also be >= thr
            atomicOr(&flagArr[row], 1);
            int pos = atomicAdd(&cnt[row], 1);
            if (pos < 16) list[row][pos] = (kp[s] >> 16) & 0xffff;
        }
    }
    __syncthreads();

    if (tid < BM) {
        int c = cnt[tid];
        int f = flagArr[tid] | (c > NCAND);
        cand_cnt[m0 + tid] = (unsigned char)(f ? 255 : c);
        int n = c < NCAND ? c : NCAND;
        for (int j = 0; j < n; ++j) cand_k[(size_t)(m0 + tid) * NCAND + j] = list[tid][j];
    }
}

// ---------------- kernel 3: rescore + gather / zq_st / per-row loss / idx ----------------
__global__ __launch_bounds__(256) void k_final(const float* __restrict__ z,
                                               const float* __restrict__ E,
                                               const float* __restrict__ En,
                                               const unsigned char* __restrict__ cand_cnt,
                                               const int* __restrict__ cand_k,
                                               float* __restrict__ out,
                                               float* __restrict__ rowloss) {
    int wid  = threadIdx.x >> 6;
    int lane = threadIdx.x & 63;
    int m    = blockIdx.x * 4 + wid;

    const float* zr = z + (size_t)m * DDIM;
    const float4 zz = *(const float4*)&zr[lane * 4];

    // ---- exact fp32 argmax over candidate set (or full scan if flagged) ----
    int   c  = cand_cnt[m];
    float bv = -FLT_MAX;
    int   bk = 0x7fffffff;
    if (c != 255) {
        for (int j = 0; j < c; ++j) {
            int k = cand_k[(size_t)m * NCAND + j];
            const float4 ee = *(const float4*)&En[(size_t)k * DDIM + lane * 4];
            float s = zz.x * ee.x + zz.y * ee.y + zz.z * ee.z + zz.w * ee.w;
#pragma unroll
            for (int off = 1; off < 64; off <<= 1) s += __shfl_xor(s, off);
            if (s > bv || (s == bv && k < bk)) { bv = s; bk = k; }
        }
    } else {
        // wave-parallel full scan (rare): lane handles k = kb+lane
        for (int kb = 0; kb < K_CODES; kb += 64) {
            int k = kb + lane;
            const float4* er = (const float4*)&En[(size_t)k * DDIM];
            float s0 = 0.f, s1 = 0.f, s2 = 0.f, s3 = 0.f;
#pragma unroll 8
            for (int d4 = 0; d4 < 64; ++d4) {
                float4 e  = er[d4];
                float4 zd = *(const float4*)&zr[d4 * 4];   // broadcast load
                s0 += zd.x * e.x; s1 += zd.y * e.y;
                s2 += zd.z * e.z; s3 += zd.w * e.w;
            }
            float s = (s0 + s1) + (s2 + s3);
            if (s > bv || (s == bv && k < bk)) { bv = s; bk = k; }
        }
#pragma unroll
        for (int off = 1; off < 64; off <<= 1) {
            float ov = __shfl_xor(bv, off);
            int   ok = __shfl_xor(bk, off);
            if (ov > bv || (ov == bv && ok < bk)) { bv = ov; bk = ok; }
        }
    }
    const int idx = bk;

    // ---- gather + straight-through + per-row loss ----
    const float* er = E + (size_t)idx * DDIM;
    float zv[4], ev[4];
    float sz = 0.f, se = 0.f;
#pragma unroll
    for (int p = 0; p < 4; ++p) {
        zv[p] = zr[lane + 64 * p]; sz += zv[p] * zv[p];
        ev[p] = er[lane + 64 * p]; se += ev[p] * ev[p];
    }
#pragma unroll
    for (int off = 32; off >= 1; off >>= 1) {
        sz += __shfl_xor(sz, off);
        se += __shfl_xor(se, off);
    }
    float nz = fmaxf(sqrtf(sz), 1e-8f);
    float ne = fmaxf(sqrtf(se), 1e-8f);

    float rs = 0.f;
    float* zq = out + 1 + (size_t)m * DDIM;
#pragma unroll
    for (int p = 0; p < 4; ++p) {
        float zn = zv[p] / nz;
        float en = ev[p] / ne;
        float d  = en - zn;
        rs += d * d;
        zq[lane + 64 * p] = zv[p] + (ev[p] - zv[p]);
    }
#pragma unroll
    for (int off = 32; off >= 1; off >>= 1) rs += __shfl_xor(rs, off);

    if (lane == 0) {
        rowloss[m] = rs;
        out[1 + (size_t)M_ROWS * DDIM + m] = (float)idx;
    }
}

// ---------------- kernel 4: deterministic loss reduction ----------------
__global__ __launch_bounds__(256) void k_loss(const float* __restrict__ rowloss,
                                              float* __restrict__ out) {
    __shared__ double sm[256];
    double s = 0.0;
    for (int i = threadIdx.x; i < M_ROWS; i += 256) s += (double)rowloss[i];
    sm[threadIdx.x] = s;
    __syncthreads();
    for (int st = 128; st > 0; st >>= 1) {
        if (threadIdx.x < st) sm[threadIdx.x] += sm[threadIdx.x + st];
        __syncthreads();
    }
    if (threadIdx.x == 0) {
        float c = (float)(sm[0] / (double)((size_t)M_ROWS * DDIM));
        out[0] = c + 0.05f * c;
    }
}

extern "C" void kernel_launch(void* const* d_in, const int* in_sizes, int n_in,
                              void* d_out, int out_size, void* d_ws, size_t ws_size,
                              hipStream_t stream) {
    const float* z = (const float*)d_in[0];
    const float* E = (const float*)d_in[1];
    float* out = (float*)d_out;

    char* ws = (char*)d_ws;
    size_t off = 0;
    float*          En       = (float*)(ws + off);          off += (size_t)K_CODES * DDIM * 4;   // 8 MB
    unsigned short* En_b     = (unsigned short*)(ws + off); off += (size_t)K_CODES * DDIM * 2;   // 4 MB
    unsigned short* z_nb     = (unsigned short*)(ws + off); off += (size_t)M_ROWS * DDIM * 2;    // 16 MB
    int*            cand_k   = (int*)(ws + off);            off += (size_t)M_ROWS * NCAND * 4;   // 1 MB
    unsigned char*  cand_cnt = (unsigned char*)(ws + off);  off += (size_t)M_ROWS;               // 32 KB
    float*          rowloss  = (float*)(ws + off);

    k_norm_E<<<K_CODES / 4, 256, 0, stream>>>(E, En, En_b);
    k_norm_z<<<M_ROWS / 4, 256, 0, stream>>>(z, z_nb);
    k_cand<<<M_ROWS / BM, 512, 0, stream>>>(z_nb, En_b, cand_cnt, cand_k);
    k_final<<<M_ROWS / 4, 256, 0, stream>>>(z, E, En, cand_cnt, cand_k, out, rowloss);
    k_loss<<<1, 256, 0, stream>>>(rowloss, out);
}

// Round 6
// 538.938 us; speedup vs baseline: 5.8794x; 5.8794x over previous
//
#include <hip/hip_runtime.h>
#include <float.h>
#include <math.h>
#include <stdint.h>

#define M_ROWS 32768
#define K_CODES 8192
#define DDIM 256
#define BM 64
#define BN 64
#define NTILES (K_CODES / BN)   // 128
#define DELTA 0.009f
#define CAP 16

typedef __attribute__((ext_vector_type(8))) short short8;
typedef __attribute__((ext_vector_type(4))) float f32x4;

__device__ inline unsigned short f2bf(float f) {
    unsigned u = __float_as_uint(f);
    return (unsigned short)((u + 0x7fffu + ((u >> 16) & 1u)) >> 16);
}
__device__ inline unsigned fkey(float f) {
    unsigned u = __float_as_uint(f);
    return u ^ ((unsigned)((int)u >> 31) | 0x80000000u);
}
__device__ inline float fkey_inv(unsigned k) {
    unsigned u = (k & 0x80000000u) ? (k ^ 0x80000000u) : ~k;
    return __uint_as_float(u);
}

#define GLOAD16(gsrc, ldst)                                                     \
    __builtin_amdgcn_global_load_lds(                                           \
        (const __attribute__((address_space(1))) void*)(gsrc),                  \
        (__attribute__((address_space(3))) void*)(ldst), 16, 0, 0)

// ---------------- kernel 1: normalize E -> En (fp32) + En_b (bf16) ----------------
__global__ __launch_bounds__(256) void k_norm_E(const float* __restrict__ E,
                                                float* __restrict__ En,
                                                unsigned short* __restrict__ En_b) {
    int wid  = threadIdx.x >> 6;
    int lane = threadIdx.x & 63;
    int row  = blockIdx.x * 4 + wid;
    const float* e = E + (size_t)row * DDIM;
    float v[4];
    float ssq = 0.f;
#pragma unroll
    for (int p = 0; p < 4; ++p) { v[p] = e[lane + 64 * p]; ssq += v[p] * v[p]; }
#pragma unroll
    for (int off = 32; off >= 1; off >>= 1) ssq += __shfl_xor(ssq, off);
    float inv = 1.f / fmaxf(sqrtf(ssq), 1e-8f);
    float* o = En + (size_t)row * DDIM;
    unsigned short* ob = En_b + (size_t)row * DDIM;
#pragma unroll
    for (int p = 0; p < 4; ++p) {
        float nv = v[p] * inv;
        o[lane + 64 * p]  = nv;
        ob[lane + 64 * p] = f2bf(nv);
    }
}

// ---------------- kernel 2: two-pass MFMA filter ----------------
// 512 thr = 8 waves: wr=wid>>2 (row half of BM=64), wc=wid&3 (col 16-group).
// Pass A: all 128 tiles, register fmax only -> exact row max.
// Pass B: recompute tiles, emit every k with sim >= rowmax - DELTA.
// Depth-2 prefetch: 3 LDS buffers, raw s_barrier + counted vmcnt(4).
__global__ __launch_bounds__(512, 2) void k_cand(
    const float* __restrict__ z,
    const unsigned short* __restrict__ En_b,
    unsigned char* __restrict__ cand_cnt,
    int* __restrict__ cand_k) {

    __shared__ __attribute__((aligned(16))) char Bs[3][32768];   // 96 KB
    __shared__ unsigned rowmaxKey[BM];
    __shared__ int cnt[BM];
    __shared__ int list[BM][CAP];                                 // 4 KB

    const int tid  = threadIdx.x;
    const int lane = tid & 63;
    const int wid  = tid >> 6;
    const int wr   = wid >> 2;
    const int wc   = wid & 3;
    const int lo   = lane & 15;
    const int hi   = lane >> 4;
    const int m0   = blockIdx.x * BM;

    if (tid < BM) { cnt[tid] = 0; rowmaxKey[tid] = 0u; }

    const char* eb = (const char*)En_b;

    // ---- stage helper: tile kt (32 KB) into bufp ----
    auto stage = [&](int ktile, char* bufp) {
#pragma unroll
        for (int i = 0; i < 4; ++i) {
            int chunk = i * 8 + wid;            // 0..31
            int G   = chunk * 64 + lane;
            int row = G >> 5;
            int g   = (G & 31) ^ (row & 7);
            GLOAD16(eb + (size_t)(ktile * BN + row) * 512 + g * 16, bufp + chunk * 1024);
        }
    };

    // ---- A fragments: load z fp32, normalize in-register, cvt bf16 ----
    short8 af[2][8];
#pragma unroll
    for (int mi = 0; mi < 2; ++mi) {
        const float* zr = z + (size_t)(m0 + wr * 32 + mi * 16 + lo) * DDIM;
        float4 v[16];
        float ssq = 0.f;
#pragma unroll
        for (int ks = 0; ks < 8; ++ks) {
            int e0 = (ks * 4 + hi) * 8;
            v[2 * ks]     = *(const float4*)&zr[e0];
            v[2 * ks + 1] = *(const float4*)&zr[e0 + 4];
            float4 a = v[2 * ks], b = v[2 * ks + 1];
            ssq += a.x * a.x + a.y * a.y + a.z * a.z + a.w * a.w;
            ssq += b.x * b.x + b.y * b.y + b.z * b.z + b.w * b.w;
        }
        // full row ssq: 4 hi-lanes hold disjoint 64-element sets
        ssq += __shfl_xor(ssq, 16);
        ssq += __shfl_xor(ssq, 32);
        float inv = 1.f / fmaxf(sqrtf(ssq), 1e-8f);
#pragma unroll
        for (int ks = 0; ks < 8; ++ks) {
            float4 a = v[2 * ks], b = v[2 * ks + 1];
            short8 s8;
            s8[0] = (short)f2bf(a.x * inv); s8[1] = (short)f2bf(a.y * inv);
            s8[2] = (short)f2bf(a.z * inv); s8[3] = (short)f2bf(a.w * inv);
            s8[4] = (short)f2bf(b.x * inv); s8[5] = (short)f2bf(b.y * inv);
            s8[6] = (short)f2bf(b.z * inv); s8[7] = (short)f2bf(b.w * inv);
            af[mi][ks] = s8;
        }
    }

    const int brow = wc * 16 + lo;
    const int bsw  = brow & 7;

    // ================= PASS A: row max =================
    float pmax[8];
#pragma unroll
    for (int s = 0; s < 8; ++s) pmax[s] = -FLT_MAX;

    stage(0, &Bs[0][0]);
    stage(1, &Bs[1][0]);

    for (int t = 0; t < NTILES; ++t) {
        if (t < NTILES - 1) asm volatile("s_waitcnt vmcnt(4)" ::: "memory");
        else                asm volatile("s_waitcnt vmcnt(0)" ::: "memory");
        __builtin_amdgcn_s_barrier();
        __builtin_amdgcn_sched_barrier(0);
        if (t + 2 < NTILES) stage(t + 2, &Bs[(t + 2) % 3][0]);

        f32x4 acc[2];
        acc[0] = (f32x4){0.f, 0.f, 0.f, 0.f};
        acc[1] = (f32x4){0.f, 0.f, 0.f, 0.f};
        const unsigned short* Bc = (const unsigned short*)&Bs[t % 3][0];
#pragma unroll
        for (int ks = 0; ks < 8; ++ks) {
            int g = (ks * 4 + hi) ^ bsw;
            short8 bf = *(const short8*)&Bc[brow * 256 + g * 8];
            acc[0] = __builtin_amdgcn_mfma_f32_16x16x32_bf16(af[0][ks], bf, acc[0], 0, 0, 0);
            acc[1] = __builtin_amdgcn_mfma_f32_16x16x32_bf16(af[1][ks], bf, acc[1], 0, 0, 0);
        }
#pragma unroll
        for (int mi = 0; mi < 2; ++mi)
#pragma unroll
            for (int r = 0; r < 4; ++r)
                pmax[mi * 4 + r] = fmaxf(pmax[mi * 4 + r], acc[mi][r]);
    }

    // reduce row max across the 16 lo-lanes, publish via LDS atomicMax
#pragma unroll
    for (int s = 0; s < 8; ++s) {
        float w = pmax[s];
        w = fmaxf(w, __shfl_xor(w, 1));
        w = fmaxf(w, __shfl_xor(w, 2));
        w = fmaxf(w, __shfl_xor(w, 4));
        w = fmaxf(w, __shfl_xor(w, 8));
        if (lo == 0) {
            int row = wr * 32 + (s >> 2) * 16 + hi * 4 + (s & 3);
            atomicMax(&rowmaxKey[row], fkey(w));
        }
    }
    asm volatile("s_waitcnt lgkmcnt(0)" ::: "memory");
    __builtin_amdgcn_s_barrier();
    __builtin_amdgcn_sched_barrier(0);

    float thr[8];
#pragma unroll
    for (int s = 0; s < 8; ++s) {
        int row = wr * 32 + (s >> 2) * 16 + hi * 4 + (s & 3);
        thr[s] = fkey_inv(rowmaxKey[row]) - DELTA;
    }

    // ================= PASS B: emit candidates =================
    stage(0, &Bs[0][0]);
    stage(1, &Bs[1][0]);

    for (int t = 0; t < NTILES; ++t) {
        if (t < NTILES - 1) asm volatile("s_waitcnt vmcnt(4)" ::: "memory");
        else                asm volatile("s_waitcnt vmcnt(0)" ::: "memory");
        __builtin_amdgcn_s_barrier();
        __builtin_amdgcn_sched_barrier(0);
        if (t + 2 < NTILES) stage(t + 2, &Bs[(t + 2) % 3][0]);

        f32x4 acc[2];
        acc[0] = (f32x4){0.f, 0.f, 0.f, 0.f};
        acc[1] = (f32x4){0.f, 0.f, 0.f, 0.f};
        const unsigned short* Bc = (const unsigned short*)&Bs[t % 3][0];
#pragma unroll
        for (int ks = 0; ks < 8; ++ks) {
            int g = (ks * 4 + hi) ^ bsw;
            short8 bf = *(const short8*)&Bc[brow * 256 + g * 8];
            acc[0] = __builtin_amdgcn_mfma_f32_16x16x32_bf16(af[0][ks], bf, acc[0], 0, 0, 0);
            acc[1] = __builtin_amdgcn_mfma_f32_16x16x32_bf16(af[1][ks], bf, acc[1], 0, 0, 0);
        }
        const int kv = t * BN + wc * 16 + lo;
#pragma unroll
        for (int mi = 0; mi < 2; ++mi)
#pragma unroll
            for (int r = 0; r < 4; ++r) {
                if (acc[mi][r] >= thr[mi * 4 + r]) {
                    int row = wr * 32 + mi * 16 + hi * 4 + r;
                    int pos = atomicAdd(&cnt[row], 1);
                    if (pos < CAP) list[row][pos] = kv;
                }
            }
    }
    __syncthreads();   // full drain: lists complete

    if (tid < BM) {
        int c = cnt[tid];
        cand_cnt[m0 + tid] = (unsigned char)(c > CAP ? 255 : c);
        int n = c < CAP ? c : CAP;
        for (int j = 0; j < n; ++j) cand_k[(size_t)(m0 + tid) * CAP + j] = list[tid][j];
    }
}

// ---------------- kernel 3: rescore + gather / zq_st / per-row loss / idx ----------------
__global__ __launch_bounds__(256) void k_final(const float* __restrict__ z,
                                               const float* __restrict__ E,
                                               const float* __restrict__ En,
                                               const unsigned char* __restrict__ cand_cnt,
                                               const int* __restrict__ cand_k,
                                               float* __restrict__ out,
                                               float* __restrict__ rowloss) {
    __shared__ float zl[4][256];
    int wid  = threadIdx.x >> 6;
    int lane = threadIdx.x & 63;
    int m    = blockIdx.x * 4 + wid;

    const float* zr = z + (size_t)m * DDIM;
    const float4 zz = *(const float4*)&zr[lane * 4];

    int   c  = cand_cnt[m];
    float bv = -FLT_MAX;
    int   bk = 0x7fffffff;
    if (c != 255) {
        for (int j = 0; j < c; ++j) {
            int k = cand_k[(size_t)m * CAP + j];
            const float4 ee = *(const float4*)&En[(size_t)k * DDIM + lane * 4];
            float s = zz.x * ee.x + zz.y * ee.y + zz.z * ee.z + zz.w * ee.w;
#pragma unroll
            for (int off = 1; off < 64; off <<= 1) s += __shfl_xor(s, off);
            if (s > bv || (s == bv && k < bk)) { bv = s; bk = k; }
        }
    } else {
        // insurance fallback: wave-parallel full fp32 scan, z staged in LDS
        *(float4*)&zl[wid][lane * 4] = zz;
        asm volatile("s_waitcnt lgkmcnt(0)" ::: "memory");
        for (int kb = 0; kb < K_CODES; kb += 64) {
            int k = kb + lane;
            const float4* er = (const float4*)&En[(size_t)k * DDIM];
            float s0 = 0.f, s1 = 0.f, s2 = 0.f, s3 = 0.f;
#pragma unroll 8
            for (int d4 = 0; d4 < 64; ++d4) {
                float4 e  = er[d4];
                float4 zd = *(const float4*)&zl[wid][d4 * 4];
                s0 += zd.x * e.x; s1 += zd.y * e.y;
                s2 += zd.z * e.z; s3 += zd.w * e.w;
            }
            float s = (s0 + s1) + (s2 + s3);
            if (s > bv || (s == bv && k < bk)) { bv = s; bk = k; }
        }
#pragma unroll
        for (int off = 1; off < 64; off <<= 1) {
            float ov = __shfl_xor(bv, off);
            int   ok = __shfl_xor(bk, off);
            if (ov > bv || (ov == bv && ok < bk)) { bv = ov; bk = ok; }
        }
    }
    const int idx = bk;

    const float* er = E + (size_t)idx * DDIM;
    float zv[4], ev[4];
    float sz = 0.f, se = 0.f;
#pragma unroll
    for (int p = 0; p < 4; ++p) {
        zv[p] = zr[lane + 64 * p]; sz += zv[p] * zv[p];
        ev[p] = er[lane + 64 * p]; se += ev[p] * ev[p];
    }
#pragma unroll
    for (int off = 32; off >= 1; off >>= 1) {
        sz += __shfl_xor(sz, off);
        se += __shfl_xor(se, off);
    }
    float nz = fmaxf(sqrtf(sz), 1e-8f);
    float ne = fmaxf(sqrtf(se), 1e-8f);

    float rs = 0.f;
    float* zq = out + 1 + (size_t)m * DDIM;
#pragma unroll
    for (int p = 0; p < 4; ++p) {
        float zn = zv[p] / nz;
        float en = ev[p] / ne;
        float d  = en - zn;
        rs += d * d;
        zq[lane + 64 * p] = zv[p] + (ev[p] - zv[p]);
    }
#pragma unroll
    for (int off = 32; off >= 1; off >>= 1) rs += __shfl_xor(rs, off);

    if (lane == 0) {
        rowloss[m] = rs;
        out[1 + (size_t)M_ROWS * DDIM + m] = (float)idx;
    }
}

// ---------------- kernel 4: deterministic loss reduction ----------------
__global__ __launch_bounds__(256) void k_loss(const float* __restrict__ rowloss,
                                              float* __restrict__ out) {
    __shared__ double sm[256];
    double s = 0.0;
    for (int i = threadIdx.x; i < M_ROWS; i += 256) s += (double)rowloss[i];
    sm[threadIdx.x] = s;
    __syncthreads();
    for (int st = 128; st > 0; st >>= 1) {
        if (threadIdx.x < st) sm[threadIdx.x] += sm[threadIdx.x + st];
        __syncthreads();
    }
    if (threadIdx.x == 0) {
        float c = (float)(sm[0] / (double)((size_t)M_ROWS * DDIM));
        out[0] = c + 0.05f * c;
    }
}

extern "C" void kernel_launch(void* const* d_in, const int* in_sizes, int n_in,
                              void* d_out, int out_size, void* d_ws, size_t ws_size,
                              hipStream_t stream) {
    const float* z = (const float*)d_in[0];
    const float* E = (const float*)d_in[1];
    float* out = (float*)d_out;

    char* ws = (char*)d_ws;
    size_t off = 0;
    float*          En       = (float*)(ws + off);          off += (size_t)K_CODES * DDIM * 4;  // 8 MB
    unsigned short* En_b     = (unsigned short*)(ws + off); off += (size_t)K_CODES * DDIM * 2;  // 4 MB
    int*            cand_k   = (int*)(ws + off);            off += (size_t)M_ROWS * CAP * 4;    // 2 MB
    unsigned char*  cand_cnt = (unsigned char*)(ws + off);  off += (size_t)M_ROWS;              // 32 KB
    float*          rowloss  = (float*)(ws + off);

    k_norm_E<<<K_CODES / 4, 256, 0, stream>>>(E, En, En_b);
    k_cand<<<M_ROWS / BM, 512, 0, stream>>>(z, En_b, cand_cnt, cand_k);
    k_final<<<M_ROWS / 4, 256, 0, stream>>>(z, E, En, cand_cnt, cand_k, out, rowloss);
    k_loss<<<1, 256, 0, stream>>>(rowloss, out);
}

// Round 7
// 441.257 us; speedup vs baseline: 7.1809x; 1.2214x over previous
//
#include <hip/hip_runtime.h>
#include <float.h>
#include <math.h>
#include <stdint.h>

#define M_ROWS 32768
#define K_CODES 8192
#define DDIM 256
#define BM 128
#define BN 64
#define NTILES (K_CODES / BN)   // 128
#define DELTA 0.009f
#define CAP 16

typedef __attribute__((ext_vector_type(8))) short short8;
typedef __attribute__((ext_vector_type(4))) float f32x4;

__device__ inline unsigned short f2bf(float f) {
    unsigned u = __float_as_uint(f);
    return (unsigned short)((u + 0x7fffu + ((u >> 16) & 1u)) >> 16);
}
__device__ inline unsigned fkey(float f) {
    unsigned u = __float_as_uint(f);
    return u ^ ((unsigned)((int)u >> 31) | 0x80000000u);
}
__device__ inline float fkey_inv(unsigned k) {
    unsigned u = (k & 0x80000000u) ? (k ^ 0x80000000u) : ~k;
    return __uint_as_float(u);
}

#define GLOAD16(gsrc, ldst)                                                     \
    __builtin_amdgcn_global_load_lds(                                           \
        (const __attribute__((address_space(1))) void*)(gsrc),                  \
        (__attribute__((address_space(3))) void*)(ldst), 16, 0, 0)

// ---------------- kernel 1: normalize E -> En (fp32) + En_b (bf16) ----------------
__global__ __launch_bounds__(256) void k_norm_E(const float* __restrict__ E,
                                                float* __restrict__ En,
                                                unsigned short* __restrict__ En_b) {
    int wid  = threadIdx.x >> 6;
    int lane = threadIdx.x & 63;
    int row  = blockIdx.x * 4 + wid;
    const float* e = E + (size_t)row * DDIM;
    float v[4];
    float ssq = 0.f;
#pragma unroll
    for (int p = 0; p < 4; ++p) { v[p] = e[lane + 64 * p]; ssq += v[p] * v[p]; }
#pragma unroll
    for (int off = 32; off >= 1; off >>= 1) ssq += __shfl_xor(ssq, off);
    float inv = 1.f / fmaxf(sqrtf(ssq), 1e-8f);
    float* o = En + (size_t)row * DDIM;
    unsigned short* ob = En_b + (size_t)row * DDIM;
#pragma unroll
    for (int p = 0; p < 4; ++p) {
        float nv = v[p] * inv;
        o[lane + 64 * p]  = nv;
        ob[lane + 64 * p] = f2bf(nv);
    }
}

// ---------------- kernel 2: two-pass MFMA filter, BM=128, 1 block/CU ----------------
// 512 thr = 8 waves: wr=wid>>2 (64-row half), wc=wid&3 (col 16-group of BN=64).
// af[4]: 64 z-rows per wave in registers -> each B ds_read feeds 4 MFMAs.
// Pass A: register fmax -> exact row max. Pass B: recompute, emit sims >= max-DELTA.
// Depth-2 prefetch: 3 LDS buffers, raw s_barrier + counted vmcnt(4).
__global__ __launch_bounds__(512, 2) void k_cand(
    const float* __restrict__ z,
    const unsigned short* __restrict__ En_b,
    unsigned char* __restrict__ cand_cnt,
    int* __restrict__ cand_k) {

    __shared__ __attribute__((aligned(16))) char Bs[3][32768];   // 96 KB
    __shared__ unsigned rowmaxKey[BM];
    __shared__ int cnt[BM];
    __shared__ int list[BM][CAP];                                 // 8 KB

    const int tid  = threadIdx.x;
    const int lane = tid & 63;
    const int wid  = tid >> 6;
    const int wr   = wid >> 2;
    const int wc   = wid & 3;
    const int lo   = lane & 15;
    const int hi   = lane >> 4;
    const int m0   = blockIdx.x * BM;

    if (tid < BM) { cnt[tid] = 0; rowmaxKey[tid] = 0u; }

    const char* eb = (const char*)En_b;

    auto stage = [&](int ktile, char* bufp) {
#pragma unroll
        for (int i = 0; i < 4; ++i) {
            int chunk = i * 8 + wid;            // 0..31 (1 KB chunks)
            int G   = chunk * 64 + lane;
            int row = G >> 5;
            int g   = (G & 31) ^ (row & 7);
            GLOAD16(eb + (size_t)(ktile * BN + row) * 512 + g * 16, bufp + chunk * 1024);
        }
    };

    // issue first two tile stages early (overlap with z normalize)
    stage(0, &Bs[0][0]);
    stage(1, &Bs[1][0]);

    // ---- A fragments: load z fp32, normalize in-register, cvt bf16 ----
    // af[mi][ks]: row = wr*64 + mi*16 + lo
    short8 af[4][8];
#pragma unroll
    for (int mi = 0; mi < 4; ++mi) {
        const float* zr = z + (size_t)(m0 + wr * 64 + mi * 16 + lo) * DDIM;
        float4 v[16];
        float ssq = 0.f;
#pragma unroll
        for (int ks = 0; ks < 8; ++ks) {
            int e0 = (ks * 4 + hi) * 8;
            v[2 * ks]     = *(const float4*)&zr[e0];
            v[2 * ks + 1] = *(const float4*)&zr[e0 + 4];
            float4 a = v[2 * ks], b = v[2 * ks + 1];
            ssq += a.x * a.x + a.y * a.y + a.z * a.z + a.w * a.w;
            ssq += b.x * b.x + b.y * b.y + b.z * b.z + b.w * b.w;
        }
        // 4 hi-lanes hold disjoint 64-element subsets of the row
        ssq += __shfl_xor(ssq, 16);
        ssq += __shfl_xor(ssq, 32);
        float inv = 1.f / fmaxf(sqrtf(ssq), 1e-8f);
#pragma unroll
        for (int ks = 0; ks < 8; ++ks) {
            float4 a = v[2 * ks], b = v[2 * ks + 1];
            short8 s8;
            s8[0] = (short)f2bf(a.x * inv); s8[1] = (short)f2bf(a.y * inv);
            s8[2] = (short)f2bf(a.z * inv); s8[3] = (short)f2bf(a.w * inv);
            s8[4] = (short)f2bf(b.x * inv); s8[5] = (short)f2bf(b.y * inv);
            s8[6] = (short)f2bf(b.z * inv); s8[7] = (short)f2bf(b.w * inv);
            af[mi][ks] = s8;
        }
    }

    const int brow = wc * 16 + lo;
    const int bsw  = brow & 7;

    // ================= PASS A: exact row max =================
    float pmax[16];
#pragma unroll
    for (int s = 0; s < 16; ++s) pmax[s] = -FLT_MAX;

    for (int t = 0; t < NTILES; ++t) {
        if (t < NTILES - 1) asm volatile("s_waitcnt vmcnt(4)" ::: "memory");
        else                asm volatile("s_waitcnt vmcnt(0)" ::: "memory");
        __builtin_amdgcn_s_barrier();
        __builtin_amdgcn_sched_barrier(0);
        if (t + 2 < NTILES) stage(t + 2, &Bs[(t + 2) % 3][0]);

        f32x4 acc[4];
#pragma unroll
        for (int mi = 0; mi < 4; ++mi) acc[mi] = (f32x4){0.f, 0.f, 0.f, 0.f};
        const unsigned short* Bc = (const unsigned short*)&Bs[t % 3][0];
#pragma unroll
        for (int ks = 0; ks < 8; ++ks) {
            int g = (ks * 4 + hi) ^ bsw;
            short8 bf = *(const short8*)&Bc[brow * 256 + g * 8];
#pragma unroll
            for (int mi = 0; mi < 4; ++mi)
                acc[mi] = __builtin_amdgcn_mfma_f32_16x16x32_bf16(af[mi][ks], bf, acc[mi], 0, 0, 0);
        }
#pragma unroll
        for (int mi = 0; mi < 4; ++mi)
#pragma unroll
            for (int r = 0; r < 4; ++r)
                pmax[mi * 4 + r] = fmaxf(pmax[mi * 4 + r], acc[mi][r]);
    }

    // reduce row max across the 16 lo-lanes, publish via LDS atomicMax
#pragma unroll
    for (int s = 0; s < 16; ++s) {
        float w = pmax[s];
        w = fmaxf(w, __shfl_xor(w, 1));
        w = fmaxf(w, __shfl_xor(w, 2));
        w = fmaxf(w, __shfl_xor(w, 4));
        w = fmaxf(w, __shfl_xor(w, 8));
        if (lo == 0) {
            int row = wr * 64 + (s >> 2) * 16 + hi * 4 + (s & 3);
            atomicMax(&rowmaxKey[row], fkey(w));
        }
    }
    asm volatile("s_waitcnt lgkmcnt(0)" ::: "memory");
    __builtin_amdgcn_s_barrier();
    __builtin_amdgcn_sched_barrier(0);

    float thr[16];
#pragma unroll
    for (int s = 0; s < 16; ++s) {
        int row = wr * 64 + (s >> 2) * 16 + hi * 4 + (s & 3);
        thr[s] = fkey_inv(rowmaxKey[row]) - DELTA;
    }

    // ================= PASS B: emit candidates =================
    stage(0, &Bs[0][0]);
    stage(1, &Bs[1][0]);

    for (int t = 0; t < NTILES; ++t) {
        if (t < NTILES - 1) asm volatile("s_waitcnt vmcnt(4)" ::: "memory");
        else                asm volatile("s_waitcnt vmcnt(0)" ::: "memory");
        __builtin_amdgcn_s_barrier();
        __builtin_amdgcn_sched_barrier(0);
        if (t + 2 < NTILES) stage(t + 2, &Bs[(t + 2) % 3][0]);

        f32x4 acc[4];
#pragma unroll
        for (int mi = 0; mi < 4; ++mi) acc[mi] = (f32x4){0.f, 0.f, 0.f, 0.f};
        const unsigned short* Bc = (const unsigned short*)&Bs[t % 3][0];
#pragma unroll
        for (int ks = 0; ks < 8; ++ks) {
            int g = (ks * 4 + hi) ^ bsw;
            short8 bf = *(const short8*)&Bc[brow * 256 + g * 8];
#pragma unroll
            for (int mi = 0; mi < 4; ++mi)
                acc[mi] = __builtin_amdgcn_mfma_f32_16x16x32_bf16(af[mi][ks], bf, acc[mi], 0, 0, 0);
        }
        const int kv = t * BN + wc * 16 + lo;
#pragma unroll
        for (int mi = 0; mi < 4; ++mi)
#pragma unroll
            for (int r = 0; r < 4; ++r) {
                if (acc[mi][r] >= thr[mi * 4 + r]) {
                    int row = wr * 64 + mi * 16 + hi * 4 + r;
                    int pos = atomicAdd(&cnt[row], 1);
                    if (pos < CAP) list[row][pos] = kv;
                }
            }
    }
    __syncthreads();   // lists complete

    if (tid < BM) {
        int c = cnt[tid];
        cand_cnt[m0 + tid] = (unsigned char)(c > CAP ? 255 : c);
        int n = c < CAP ? c : CAP;
        for (int j = 0; j < n; ++j) cand_k[(size_t)(m0 + tid) * CAP + j] = list[tid][j];
    }
}

// ---------------- kernel 3: rescore + gather / zq_st / per-row loss / idx ----------------
__global__ __launch_bounds__(256) void k_final(const float* __restrict__ z,
                                               const float* __restrict__ E,
                                               const float* __restrict__ En,
                                               const unsigned char* __restrict__ cand_cnt,
                                               const int* __restrict__ cand_k,
                                               float* __restrict__ out,
                                               float* __restrict__ rowloss) {
    __shared__ float zl[4][256];
    int wid  = threadIdx.x >> 6;
    int lane = threadIdx.x & 63;
    int m    = blockIdx.x * 4 + wid;

    const float* zr = z + (size_t)m * DDIM;
    const float4 zz = *(const float4*)&zr[lane * 4];

    int   c  = cand_cnt[m];
    float bv = -FLT_MAX;
    int   bk = 0x7fffffff;
    if (c != 255) {
        for (int j = 0; j < c; ++j) {
            int k = cand_k[(size_t)m * CAP + j];
            const float4 ee = *(const float4*)&En[(size_t)k * DDIM + lane * 4];
            float s = zz.x * ee.x + zz.y * ee.y + zz.z * ee.z + zz.w * ee.w;
#pragma unroll
            for (int off = 1; off < 64; off <<= 1) s += __shfl_xor(s, off);
            if (s > bv || (s == bv && k < bk)) { bv = s; bk = k; }
        }
    } else {
        // insurance fallback: wave-parallel full fp32 scan, z staged in LDS
        *(float4*)&zl[wid][lane * 4] = zz;
        asm volatile("s_waitcnt lgkmcnt(0)" ::: "memory");
        for (int kb = 0; kb < K_CODES; kb += 64) {
            int k = kb + lane;
            const float4* er = (const float4*)&En[(size_t)k * DDIM];
            float s0 = 0.f, s1 = 0.f, s2 = 0.f, s3 = 0.f;
#pragma unroll 8
            for (int d4 = 0; d4 < 64; ++d4) {
                float4 e  = er[d4];
                float4 zd = *(const float4*)&zl[wid][d4 * 4];
                s0 += zd.x * e.x; s1 += zd.y * e.y;
                s2 += zd.z * e.z; s3 += zd.w * e.w;
            }
            float s = (s0 + s1) + (s2 + s3);
            if (s > bv || (s == bv && k < bk)) { bv = s; bk = k; }
        }
#pragma unroll
        for (int off = 1; off < 64; off <<= 1) {
            float ov = __shfl_xor(bv, off);
            int   ok = __shfl_xor(bk, off);
            if (ov > bv || (ov == bv && ok < bk)) { bv = ov; bk = ok; }
        }
    }
    const int idx = bk;

    const float* er = E + (size_t)idx * DDIM;
    float zv[4], ev[4];
    float sz = 0.f, se = 0.f;
#pragma unroll
    for (int p = 0; p < 4; ++p) {
        zv[p] = zr[lane + 64 * p]; sz += zv[p] * zv[p];
        ev[p] = er[lane + 64 * p]; se += ev[p] * ev[p];
    }
#pragma unroll
    for (int off = 32; off >= 1; off >>= 1) {
        sz += __shfl_xor(sz, off);
        se += __shfl_xor(se, off);
    }
    float nz = fmaxf(sqrtf(sz), 1e-8f);
    float ne = fmaxf(sqrtf(se), 1e-8f);

    float rs = 0.f;
    float* zq = out + 1 + (size_t)m * DDIM;
#pragma unroll
    for (int p = 0; p < 4; ++p) {
        float zn = zv[p] / nz;
        float en = ev[p] / ne;
        float d  = en - zn;
        rs += d * d;
        zq[lane + 64 * p] = zv[p] + (ev[p] - zv[p]);
    }
#pragma unroll
    for (int off = 32; off >= 1; off >>= 1) rs += __shfl_xor(rs, off);

    if (lane == 0) {
        rowloss[m] = rs;
        out[1 + (size_t)M_ROWS * DDIM + m] = (float)idx;
    }
}

// ---------------- kernel 4: deterministic loss reduction ----------------
__global__ __launch_bounds__(256) void k_loss(const float* __restrict__ rowloss,
                                              float* __restrict__ out) {
    __shared__ double sm[256];
    double s = 0.0;
    for (int i = threadIdx.x; i < M_ROWS; i += 256) s += (double)rowloss[i];
    sm[threadIdx.x] = s;
    __syncthreads();
    for (int st = 128; st > 0; st >>= 1) {
        if (threadIdx.x < st) sm[threadIdx.x] += sm[threadIdx.x + st];
        __syncthreads();
    }
    if (threadIdx.x == 0) {
        float c = (float)(sm[0] / (double)((size_t)M_ROWS * DDIM));
        out[0] = c + 0.05f * c;
    }
}

extern "C" void kernel_launch(void* const* d_in, const int* in_sizes, int n_in,
                              void* d_out, int out_size, void* d_ws, size_t ws_size,
                              hipStream_t stream) {
    const float* z = (const float*)d_in[0];
    const float* E = (const float*)d_in[1];
    float* out = (float*)d_out;

    char* ws = (char*)d_ws;
    size_t off = 0;
    float*          En       = (float*)(ws + off);          off += (size_t)K_CODES * DDIM * 4;  // 8 MB
    unsigned short* En_b     = (unsigned short*)(ws + off); off += (size_t)K_CODES * DDIM * 2;  // 4 MB
    int*            cand_k   = (int*)(ws + off);            off += (size_t)M_ROWS * CAP * 4;    // 2 MB
    unsigned char*  cand_cnt = (unsigned char*)(ws + off);  off += (size_t)M_ROWS;              // 32 KB
    float*          rowloss  = (float*)(ws + off);

    k_norm_E<<<K_CODES / 4, 256, 0, stream>>>(E, En, En_b);
    k_cand<<<M_ROWS / BM, 512, 0, stream>>>(z, En_b, cand_cnt, cand_k);
    k_final<<<M_ROWS / 4, 256, 0, stream>>>(z, E, En, cand_cnt, cand_k, out, rowloss);
    k_loss<<<1, 256, 0, stream>>>(rowloss, out);
}

// Round 8
// 353.120 us; speedup vs baseline: 8.9732x; 1.2496x over previous
//
#include <hip/hip_runtime.h>
#include <float.h>
#include <math.h>
#include <stdint.h>

#define M_ROWS 32768
#define K_CODES 8192
#define DDIM 256
#define BM 128
#define BN 64
#define NTILES (K_CODES / BN)   // 128
#define DELTA 0.009f
#define CAP 16

typedef __attribute__((ext_vector_type(8))) short short8;
typedef __attribute__((ext_vector_type(4))) float f32x4;

__device__ inline unsigned short f2bf(float f) {
    unsigned u = __float_as_uint(f);
    return (unsigned short)((u + 0x7fffu + ((u >> 16) & 1u)) >> 16);
}
__device__ inline unsigned fkey(float f) {
    unsigned u = __float_as_uint(f);
    return u ^ ((unsigned)((int)u >> 31) | 0x80000000u);
}
__device__ inline float fkey_inv(unsigned k) {
    unsigned u = (k & 0x80000000u) ? (k ^ 0x80000000u) : ~k;
    return __uint_as_float(u);
}

#define GLOAD16(gsrc, ldst)                                                     \
    __builtin_amdgcn_global_load_lds(                                           \
        (const __attribute__((address_space(1))) void*)(gsrc),                  \
        (__attribute__((address_space(3))) void*)(ldst), 16, 0, 0)

// ---------------- kernel 1: normalize E -> En (fp32) + En_b (bf16) ----------------
__global__ __launch_bounds__(256) void k_norm_E(const float* __restrict__ E,
                                                float* __restrict__ En,
                                                unsigned short* __restrict__ En_b) {
    int wid  = threadIdx.x >> 6;
    int lane = threadIdx.x & 63;
    int row  = blockIdx.x * 4 + wid;
    const float* e = E + (size_t)row * DDIM;
    float v[4];
    float ssq = 0.f;
#pragma unroll
    for (int p = 0; p < 4; ++p) { v[p] = e[lane + 64 * p]; ssq += v[p] * v[p]; }
#pragma unroll
    for (int off = 32; off >= 1; off >>= 1) ssq += __shfl_xor(ssq, off);
    float inv = 1.f / fmaxf(sqrtf(ssq), 1e-8f);
    float* o = En + (size_t)row * DDIM;
    unsigned short* ob = En_b + (size_t)row * DDIM;
#pragma unroll
    for (int p = 0; p < 4; ++p) {
        float nv = v[p] * inv;
        o[lane + 64 * p]  = nv;
        ob[lane + 64 * p] = f2bf(nv);
    }
}

// ---------------- kernel 2: two-pass MFMA filter, barrier-free wave pipeline ----
// 512 thr = 8 waves: wr=wid>>2 (64-row half of BM=128), wc=wid&3 (16-code group).
// Each wave stages its OWN 8KB B-slice (16 codes x 256 dims) per tile into a
// private 2x8KB LDS double buffer; counted per-wave vmcnt(8), depth-2, NO
// block barriers in the tile loops -> waves de-phase, pipes overlap.
// Pass A: register fmax -> exact row max. Pass B: recompute, emit >= max-DELTA.
__global__ __launch_bounds__(512, 2) void k_cand(
    const float* __restrict__ z,
    const unsigned short* __restrict__ En_b,
    unsigned char* __restrict__ cand_cnt,
    int* __restrict__ cand_k) {

    __shared__ __attribute__((aligned(16))) char Bw[8][2][8192];   // 128 KB
    __shared__ unsigned rowmaxKey[BM];
    __shared__ int cnt[BM];
    __shared__ int list[BM][CAP];                                   // 8 KB

    const int tid  = threadIdx.x;
    const int lane = tid & 63;
    const int wid  = tid >> 6;
    const int wr   = wid >> 2;
    const int wc   = wid & 3;
    const int lo   = lane & 15;
    const int hi   = lane >> 4;
    const int m0   = blockIdx.x * BM;

    if (tid < BM) { cnt[tid] = 0; rowmaxKey[tid] = 0u; }

    const char* eb = (const char*)En_b;
    char* b0 = &Bw[wid][0][0];
    char* b1 = &Bw[wid][1][0];

    // stage this wave's 8KB slice of tile `ktile` (16 codes owned by wc)
    auto stage = [&](int ktile, char* bufp) {
#pragma unroll
        for (int i = 0; i < 8; ++i) {
            int G   = i * 64 + lane;            // granule 0..511
            int row = G >> 5;                   // 0..15 (code within slice)
            int g   = (G & 31) ^ (row & 7);     // pre-swizzled dim-granule
            GLOAD16(eb + (size_t)(ktile * BN + wc * 16 + row) * 512 + g * 16,
                    bufp + i * 1024);
        }
    };

    // prologue staging (in flight across init barrier is fine: __syncthreads
    // drains vmcnt, costing a one-time ~L2 latency only)
    stage(0, b0);
    stage(1, b1);
    __syncthreads();   // cnt/rowmaxKey init visible to all waves

    // ---- A fragments: load z fp32, normalize in-register, cvt bf16 ----
    short8 af[4][8];
#pragma unroll
    for (int mi = 0; mi < 4; ++mi) {
        const float* zr = z + (size_t)(m0 + wr * 64 + mi * 16 + lo) * DDIM;
        float4 v[16];
        float ssq = 0.f;
#pragma unroll
        for (int ks = 0; ks < 8; ++ks) {
            int e0 = (ks * 4 + hi) * 8;
            v[2 * ks]     = *(const float4*)&zr[e0];
            v[2 * ks + 1] = *(const float4*)&zr[e0 + 4];
            float4 a = v[2 * ks], b = v[2 * ks + 1];
            ssq += a.x * a.x + a.y * a.y + a.z * a.z + a.w * a.w;
            ssq += b.x * b.x + b.y * b.y + b.z * b.z + b.w * b.w;
        }
        ssq += __shfl_xor(ssq, 16);
        ssq += __shfl_xor(ssq, 32);
        float inv = 1.f / fmaxf(sqrtf(ssq), 1e-8f);
#pragma unroll
        for (int ks = 0; ks < 8; ++ks) {
            float4 a = v[2 * ks], b = v[2 * ks + 1];
            short8 s8;
            s8[0] = (short)f2bf(a.x * inv); s8[1] = (short)f2bf(a.y * inv);
            s8[2] = (short)f2bf(a.z * inv); s8[3] = (short)f2bf(a.w * inv);
            s8[4] = (short)f2bf(b.x * inv); s8[5] = (short)f2bf(b.y * inv);
            s8[6] = (short)f2bf(b.z * inv); s8[7] = (short)f2bf(b.w * inv);
            af[mi][ks] = s8;
        }
    }

    // ================= PASS A: exact row max (no barriers) =================
    float pmax[16];
#pragma unroll
    for (int s = 0; s < 16; ++s) pmax[s] = -FLT_MAX;

    for (int t = 0; t < NTILES; ++t) {
        if (t < NTILES - 1) asm volatile("s_waitcnt vmcnt(8)" ::: "memory");
        else                asm volatile("s_waitcnt vmcnt(0)" ::: "memory");
        __builtin_amdgcn_sched_barrier(0);

        const unsigned short* Bc = (const unsigned short*)((t & 1) ? b1 : b0);
        f32x4 acc[4];
#pragma unroll
        for (int mi = 0; mi < 4; ++mi) acc[mi] = (f32x4){0.f, 0.f, 0.f, 0.f};
#pragma unroll
        for (int ks = 0; ks < 8; ++ks) {
            int g = (ks * 4 + hi) ^ (lo & 7);
            short8 bf = *(const short8*)&Bc[lo * 256 + g * 8];
#pragma unroll
            for (int mi = 0; mi < 4; ++mi)
                acc[mi] = __builtin_amdgcn_mfma_f32_16x16x32_bf16(af[mi][ks], bf, acc[mi], 0, 0, 0);
        }
#pragma unroll
        for (int mi = 0; mi < 4; ++mi)
#pragma unroll
            for (int r = 0; r < 4; ++r)
                pmax[mi * 4 + r] = fmaxf(pmax[mi * 4 + r], acc[mi][r]);

        if (t + 2 < NTILES) stage(t + 2, (t & 1) ? b1 : b0);
    }

    // reduce row max across the 16 lo-lanes, publish via LDS atomicMax
#pragma unroll
    for (int s = 0; s < 16; ++s) {
        float w = pmax[s];
        w = fmaxf(w, __shfl_xor(w, 1));
        w = fmaxf(w, __shfl_xor(w, 2));
        w = fmaxf(w, __shfl_xor(w, 4));
        w = fmaxf(w, __shfl_xor(w, 8));
        if (lo == 0) {
            int row = wr * 64 + (s >> 2) * 16 + hi * 4 + (s & 3);
            atomicMax(&rowmaxKey[row], fkey(w));
        }
    }
    __syncthreads();   // all waves' maxima published

    float thr[16];
#pragma unroll
    for (int s = 0; s < 16; ++s) {
        int row = wr * 64 + (s >> 2) * 16 + hi * 4 + (s & 3);
        thr[s] = fkey_inv(rowmaxKey[row]) - DELTA;
    }

    // ================= PASS B: emit candidates (no barriers) =================
    stage(0, b0);
    stage(1, b1);

    for (int t = 0; t < NTILES; ++t) {
        if (t < NTILES - 1) asm volatile("s_waitcnt vmcnt(8)" ::: "memory");
        else                asm volatile("s_waitcnt vmcnt(0)" ::: "memory");
        __builtin_amdgcn_sched_barrier(0);

        const unsigned short* Bc = (const unsigned short*)((t & 1) ? b1 : b0);
        f32x4 acc[4];
#pragma unroll
        for (int mi = 0; mi < 4; ++mi) acc[mi] = (f32x4){0.f, 0.f, 0.f, 0.f};
#pragma unroll
        for (int ks = 0; ks < 8; ++ks) {
            int g = (ks * 4 + hi) ^ (lo & 7);
            short8 bf = *(const short8*)&Bc[lo * 256 + g * 8];
#pragma unroll
            for (int mi = 0; mi < 4; ++mi)
                acc[mi] = __builtin_amdgcn_mfma_f32_16x16x32_bf16(af[mi][ks], bf, acc[mi], 0, 0, 0);
        }

        const int kv = t * BN + wc * 16 + lo;
#pragma unroll
        for (int mi = 0; mi < 4; ++mi)
#pragma unroll
            for (int r = 0; r < 4; ++r) {
                if (acc[mi][r] >= thr[mi * 4 + r]) {
                    int row = wr * 64 + mi * 16 + hi * 4 + r;
                    int pos = atomicAdd(&cnt[row], 1);
                    if (pos < CAP) list[row][pos] = kv;
                }
            }

        if (t + 2 < NTILES) stage(t + 2, (t & 1) ? b1 : b0);
    }
    __syncthreads();   // lists complete

    if (tid < BM) {
        int c = cnt[tid];
        cand_cnt[m0 + tid] = (unsigned char)(c > CAP ? 255 : c);
        int n = c < CAP ? c : CAP;
        for (int j = 0; j < n; ++j) cand_k[(size_t)(m0 + tid) * CAP + j] = list[tid][j];
    }
}

// ---------------- kernel 3: rescore + gather / zq_st / per-row loss / idx ----------------
__global__ __launch_bounds__(256) void k_final(const float* __restrict__ z,
                                               const float* __restrict__ E,
                                               const float* __restrict__ En,
                                               const unsigned char* __restrict__ cand_cnt,
                                               const int* __restrict__ cand_k,
                                               float* __restrict__ out,
                                               float* __restrict__ rowloss) {
    __shared__ float zl[4][256];
    int wid  = threadIdx.x >> 6;
    int lane = threadIdx.x & 63;
    int m    = blockIdx.x * 4 + wid;

    const float* zr = z + (size_t)m * DDIM;
    const float4 zz = *(const float4*)&zr[lane * 4];

    int   c  = cand_cnt[m];
    float bv = -FLT_MAX;
    int   bk = 0x7fffffff;
    if (c != 255) {
        for (int j = 0; j < c; ++j) {
            int k = cand_k[(size_t)m * CAP + j];
            const float4 ee = *(const float4*)&En[(size_t)k * DDIM + lane * 4];
            float s = zz.x * ee.x + zz.y * ee.y + zz.z * ee.z + zz.w * ee.w;
#pragma unroll
            for (int off = 1; off < 64; off <<= 1) s += __shfl_xor(s, off);
            if (s > bv || (s == bv && k < bk)) { bv = s; bk = k; }
        }
    } else {
        // insurance fallback: wave-parallel full fp32 scan, z staged in LDS
        *(float4*)&zl[wid][lane * 4] = zz;
        asm volatile("s_waitcnt lgkmcnt(0)" ::: "memory");
        for (int kb = 0; kb < K_CODES; kb += 64) {
            int k = kb + lane;
            const float4* er = (const float4*)&En[(size_t)k * DDIM];
            float s0 = 0.f, s1 = 0.f, s2 = 0.f, s3 = 0.f;
#pragma unroll 8
            for (int d4 = 0; d4 < 64; ++d4) {
                float4 e  = er[d4];
                float4 zd = *(const float4*)&zl[wid][d4 * 4];
                s0 += zd.x * e.x; s1 += zd.y * e.y;
                s2 += zd.z * e.z; s3 += zd.w * e.w;
            }
            float s = (s0 + s1) + (s2 + s3);
            if (s > bv || (s == bv && k < bk)) { bv = s; bk = k; }
        }
#pragma unroll
        for (int off = 1; off < 64; off <<= 1) {
            float ov = __shfl_xor(bv, off);
            int   ok = __shfl_xor(bk, off);
            if (ov > bv || (ov == bv && ok < bk)) { bv = ov; bk = ok; }
        }
    }
    const int idx = bk;

    const float* er = E + (size_t)idx * DDIM;
    float zv[4], ev[4];
    float sz = 0.f, se = 0.f;
#pragma unroll
    for (int p = 0; p < 4; ++p) {
        zv[p] = zr[lane + 64 * p]; sz += zv[p] * zv[p];
        ev[p] = er[lane + 64 * p]; se += ev[p] * ev[p];
    }
#pragma unroll
    for (int off = 32; off >= 1; off >>= 1) {
        sz += __shfl_xor(sz, off);
        se += __shfl_xor(se, off);
    }
    float nz = fmaxf(sqrtf(sz), 1e-8f);
    float ne = fmaxf(sqrtf(se), 1e-8f);

    float rs = 0.f;
    float* zq = out + 1 + (size_t)m * DDIM;
#pragma unroll
    for (int p = 0; p < 4; ++p) {
        float zn = zv[p] / nz;
        float en = ev[p] / ne;
        float d  = en - zn;
        rs += d * d;
        zq[lane + 64 * p] = zv[p] + (ev[p] - zv[p]);
    }
#pragma unroll
    for (int off = 32; off >= 1; off >>= 1) rs += __shfl_xor(rs, off);

    if (lane == 0) {
        rowloss[m] = rs;
        out[1 + (size_t)M_ROWS * DDIM + m] = (float)idx;
    }
}

// ---------------- kernel 4: deterministic loss reduction ----------------
__global__ __launch_bounds__(256) void k_loss(const float* __restrict__ rowloss,
                                              float* __restrict__ out) {
    __shared__ double sm[256];
    double s = 0.0;
    for (int i = threadIdx.x; i < M_ROWS; i += 256) s += (double)rowloss[i];
    sm[threadIdx.x] = s;
    __syncthreads();
    for (int st = 128; st > 0; st >>= 1) {
        if (threadIdx.x < st) sm[threadIdx.x] += sm[threadIdx.x + st];
        __syncthreads();
    }
    if (threadIdx.x == 0) {
        float c = (float)(sm[0] / (double)((size_t)M_ROWS * DDIM));
        out[0] = c + 0.05f * c;
    }
}

extern "C" void kernel_launch(void* const* d_in, const int* in_sizes, int n_in,
                              void* d_out, int out_size, void* d_ws, size_t ws_size,
                              hipStream_t stream) {
    const float* z = (const float*)d_in[0];
    const float* E = (const float*)d_in[1];
    float* out = (float*)d_out;

    char* ws = (char*)d_ws;
    size_t off = 0;
    float*          En       = (float*)(ws + off);          off += (size_t)K_CODES * DDIM * 4;  // 8 MB
    unsigned short* En_b     = (unsigned short*)(ws + off); off += (size_t)K_CODES * DDIM * 2;  // 4 MB
    int*            cand_k   = (int*)(ws + off);            off += (size_t)M_ROWS * CAP * 4;    // 2 MB
    unsigned char*  cand_cnt = (unsigned char*)(ws + off);  off += (size_t)M_ROWS;              // 32 KB
    float*          rowloss  = (float*)(ws + off);

    k_norm_E<<<K_CODES / 4, 256, 0, stream>>>(E, En, En_b);
    k_cand<<<M_ROWS / BM, 512, 0, stream>>>(z, En_b, cand_cnt, cand_k);
    k_final<<<M_ROWS / 4, 256, 0, stream>>>(z, E, En, cand_cnt, cand_k, out, rowloss);
    k_loss<<<1, 256, 0, stream>>>(rowloss, out);
}